// Round 5
// baseline (279.636 us; speedup 1.0000x reference)
//
#include <hip/hip_runtime.h>
#include <hip/hip_bf16.h>

#define N_NODES 50000
#define N_EDGES 800000
#define NUM_GRAPHS 512
#define NSCAN 196                 // ceil(N_NODES/256)
#define CNT_BLOCKS 391            // ceil(N_EDGES/8/256)

typedef short short8 __attribute__((ext_vector_type(8)));
typedef unsigned short u16x8 __attribute__((ext_vector_type(8)));
typedef float f32x4 __attribute__((ext_vector_type(4)));

__device__ __forceinline__ unsigned short f2bu(float f) {
    __hip_bfloat16 h = __float2bfloat16(f);
    return *reinterpret_cast<unsigned short*>(&h);
}
__device__ __forceinline__ float bu2f(unsigned short u) {
    unsigned int v = ((unsigned int)u) << 16;
    float f;
    __builtin_memcpy(&f, &v, 4);
    return f;
}

// ---- pass 1: degree count (atomic, no return -> no latency chain).
//      Fused: W->bf16^T conversion (tail blocks) + zero hs sentinel row. ----
__global__ __launch_bounds__(256) void count_k(const int* __restrict__ ei,
                                               int* __restrict__ cnt,
                                               const float* __restrict__ W1,
                                               const float* __restrict__ W2,
                                               unsigned short* __restrict__ W1t,
                                               unsigned short* __restrict__ W2t,
                                               unsigned short* __restrict__ hs) {
    int b = blockIdx.x;
    if (b >= CNT_BLOCKS) {  // weight transpose-convert
        int wb = b - CNT_BLOCKS;
        const float* W = wb < 64 ? W1 : W2;
        unsigned short* Wt = wb < 64 ? W1t : W2t;
        int idx = (wb & 63) * 256 + threadIdx.x;
        int k = idx >> 7, n = idx & 127;
        Wt[n * 128 + k] = f2bu(W[idx]);
        return;
    }
    if (b == 0 && threadIdx.x < 64)
        ((unsigned int*)(hs + (size_t)N_NODES * 128))[threadIdx.x] = 0u;
    int e0 = (b * 256 + threadIdx.x) * 8;
    if (e0 >= N_EDGES) return;
    const int* dd = ei + N_EDGES;
    int4 d0 = *(const int4*)(dd + e0);
    int4 d1 = *(const int4*)(dd + e0 + 4);
    atomicAdd(&cnt[d0.x], 1); atomicAdd(&cnt[d0.y], 1);
    atomicAdd(&cnt[d0.z], 1); atomicAdd(&cnt[d0.w], 1);
    atomicAdd(&cnt[d1.x], 1); atomicAdd(&cnt[d1.y], 1);
    atomicAdd(&cnt[d1.z], 1); atomicAdd(&cnt[d1.w], 1);
}

// seg(i) = (cnt+1 self + pad to x4) = (cnt+4) & ~3
__device__ __forceinline__ int seg_of(int c) { return (c + 4) & ~3; }

// ---- pass 2a: per-block segment sums ----
__global__ __launch_bounds__(256) void scan_a_k(const int* __restrict__ cnt,
                                                int* __restrict__ bsum) {
    int i = blockIdx.x * 256 + threadIdx.x;
    int se = i < N_NODES ? seg_of(cnt[i]) : 0;
#pragma unroll
    for (int o = 32; o > 0; o >>= 1) se += __shfl_down(se, o, 64);
    __shared__ int part[4];
    if ((threadIdx.x & 63) == 0) part[threadIdx.x >> 6] = se;
    __syncthreads();
    if (threadIdx.x == 0)
        bsum[blockIdx.x] = part[0] + part[1] + part[2] + part[3];
}

// ---- pass 2b: exclusive scan of the 196 block sums (one block) ----
__global__ __launch_bounds__(256) void scan_b_k(const int* __restrict__ bsum,
                                                int* __restrict__ boff) {
    __shared__ int sb[256];
    int t = threadIdx.x;
    int v = t < NSCAN ? bsum[t] : 0;
    sb[t] = v;
    __syncthreads();
    for (int off = 1; off < 256; off <<= 1) {
        int u = t >= off ? sb[t - off] : 0;
        __syncthreads();
        sb[t] += u;
        __syncthreads();
    }
    if (t < NSCAN) boff[t] = sb[t] - v;  // exclusive
}

// ---- pass 2c: per-node base, fill self-loop + sentinel pads, cursors, dinv ----
__global__ __launch_bounds__(256) void scan_c_k(const int* __restrict__ cnt,
                                                const int* __restrict__ boff,
                                                int* __restrict__ rowptr,
                                                int* __restrict__ rowcur,
                                                unsigned short* __restrict__ csr,
                                                float* __restrict__ dinv) {
    __shared__ int sb[256];
    int t = threadIdx.x, i = blockIdx.x * 256 + t;
    int c = i < N_NODES ? cnt[i] : 0;
    int se = i < N_NODES ? seg_of(c) : 0;
    sb[t] = se;
    __syncthreads();
    for (int off = 1; off < 256; off <<= 1) {
        int u = t >= off ? sb[t - off] : 0;
        __syncthreads();
        sb[t] += u;
        __syncthreads();
    }
    int base = boff[blockIdx.x] + sb[t] - se;  // exclusive
    if (i < N_NODES) {
        rowptr[i] = base;
        rowcur[i] = base;
        csr[base + c] = (unsigned short)i;  // self loop
        for (int s = c + 1; s < se; ++s) csr[base + s] = (unsigned short)N_NODES;
        dinv[i] = rsqrtf((float)c + 1.0f);
        if (i == N_NODES - 1) rowptr[N_NODES] = base + se;
    }
}

// ---- pass 3: edge scatter into dense CSR ----
__global__ __launch_bounds__(256) void scatter_k(const int* __restrict__ ei,
                                                 int* __restrict__ rowcur,
                                                 unsigned short* __restrict__ csr) {
    int e0 = (blockIdx.x * 256 + threadIdx.x) * 8;
    if (e0 >= N_EDGES) return;
    const int* dd = ei + N_EDGES;
    int4 s0 = *(const int4*)(ei + e0);
    int4 s1 = *(const int4*)(ei + e0 + 4);
    int4 d0 = *(const int4*)(dd + e0);
    int4 d1 = *(const int4*)(dd + e0 + 4);
    int p0 = atomicAdd(&rowcur[d0.x], 1);
    int p1 = atomicAdd(&rowcur[d0.y], 1);
    int p2 = atomicAdd(&rowcur[d0.z], 1);
    int p3 = atomicAdd(&rowcur[d0.w], 1);
    int p4 = atomicAdd(&rowcur[d1.x], 1);
    int p5 = atomicAdd(&rowcur[d1.y], 1);
    int p6 = atomicAdd(&rowcur[d1.z], 1);
    int p7 = atomicAdd(&rowcur[d1.w], 1);
    csr[p0] = (unsigned short)s0.x; csr[p1] = (unsigned short)s0.y;
    csr[p2] = (unsigned short)s0.z; csr[p3] = (unsigned short)s0.w;
    csr[p4] = (unsigned short)s1.x; csr[p5] = (unsigned short)s1.y;
    csr[p6] = (unsigned short)s1.z; csr[p7] = (unsigned short)s1.w;
}

// ---- GEMM: C[r][c] = bf16( dinv[r] * sum_k A[r][k]*W[k][c] ), 128 rows/block ----
template <bool F32A>
__global__ __launch_bounds__(256) void gemm_k(const void* __restrict__ Ap,
                                              const unsigned short* __restrict__ Wt,
                                              const float* __restrict__ dinv,
                                              unsigned short* __restrict__ C) {
    __shared__ unsigned short Wl[128 * 136];
    int t = threadIdx.x;
    for (int idx = t; idx < 2048; idx += 256) {
        int n = idx >> 4, c = idx & 15;
        *(u16x8*)(Wl + n * 136 + c * 8) = *(const u16x8*)(Wt + n * 128 + c * 8);
    }
    __syncthreads();

    int wave = t >> 6, lane = t & 63, quad = lane >> 4, ln = lane & 15;
    int rb = blockIdx.x * 128 + wave * 16;

    short8 a[2][4];
#pragma unroll
    for (int mt = 0; mt < 2; ++mt) {
        int r = rb + mt * 64 + ln;
        r = r < N_NODES ? r : N_NODES - 1;
        if (F32A) {
            const float* arow = (const float*)Ap + (size_t)r * 128 + quad * 8;
#pragma unroll
            for (int ks = 0; ks < 4; ++ks) {
                float4 v0 = *(const float4*)(arow + ks * 32);
                float4 v1 = *(const float4*)(arow + ks * 32 + 4);
                short8 av;
                av[0] = (short)f2bu(v0.x); av[1] = (short)f2bu(v0.y);
                av[2] = (short)f2bu(v0.z); av[3] = (short)f2bu(v0.w);
                av[4] = (short)f2bu(v1.x); av[5] = (short)f2bu(v1.y);
                av[6] = (short)f2bu(v1.z); av[7] = (short)f2bu(v1.w);
                a[mt][ks] = av;
            }
        } else {
            const unsigned short* arow = (const unsigned short*)Ap + (size_t)r * 128 + quad * 8;
#pragma unroll
            for (int ks = 0; ks < 4; ++ks) a[mt][ks] = *(const short8*)(arow + ks * 32);
        }
    }

    f32x4 acc[2][8];
#pragma unroll
    for (int mt = 0; mt < 2; ++mt)
#pragma unroll
        for (int ct = 0; ct < 8; ++ct) acc[mt][ct] = (f32x4){0.f, 0.f, 0.f, 0.f};

#pragma unroll
    for (int ks = 0; ks < 4; ++ks)
#pragma unroll
        for (int ct = 0; ct < 8; ++ct) {
            short8 b = *(const short8*)(Wl + (ct * 16 + ln) * 136 + ks * 32 + quad * 8);
            acc[0][ct] = __builtin_amdgcn_mfma_f32_16x16x32_bf16(a[0][ks], b, acc[0][ct], 0, 0, 0);
            acc[1][ct] = __builtin_amdgcn_mfma_f32_16x16x32_bf16(a[1][ks], b, acc[1][ct], 0, 0, 0);
        }

#pragma unroll
    for (int mt = 0; mt < 2; ++mt) {
#pragma unroll
        for (int rr = 0; rr < 4; ++rr) {
            int r = rb + mt * 64 + quad * 4 + rr;
            if (r >= N_NODES) continue;
            float dv = dinv[r];
#pragma unroll
            for (int ct = 0; ct < 8; ++ct)
                C[(size_t)r * 128 + ct * 16 + ln] = f2bu(acc[mt][ct][rr] * dv);
        }
    }
}

// ---- aggregation over CSR: one wave/node; quad q gathers row for edge 4i+q ----
__global__ __launch_bounds__(256) void agg_k(const unsigned short* __restrict__ hs,
                                             const unsigned short* __restrict__ csr,
                                             const int* __restrict__ rowptr,
                                             const float* __restrict__ dinv,
                                             const float* __restrict__ bias,
                                             unsigned short* __restrict__ out) {
    int wave = threadIdx.x >> 6, lane = threadIdx.x & 63;
    int node = blockIdx.x * 4 + wave;  // grid*4 == N_NODES exactly
    int quad = lane >> 4, fl = lane & 15;
    int base = rowptr[node];
    int n = rowptr[node + 1] - base;  // multiple of 4 (self + pad included)
    n = n < 64 ? n : 64;
    int idx = lane < n ? (int)csr[base + lane] : N_NODES;
    int iters = n >> 2;

    float acc[8];
#pragma unroll
    for (int j = 0; j < 8; ++j) acc[j] = 0.f;

    for (int i = 0; i < iters; ++i) {
        int s = __shfl(idx, i * 4 + quad, 64);
        u16x8 v = *(const u16x8*)(hs + (size_t)s * 128 + fl * 8);
#pragma unroll
        for (int j = 0; j < 8; ++j) acc[j] += bu2f(v[j]);
    }

#pragma unroll
    for (int j = 0; j < 8; ++j) {
        acc[j] += __shfl_xor(acc[j], 16, 64);
        acc[j] += __shfl_xor(acc[j], 32, 64);
    }

    if (quad == 0) {
        float dv = dinv[node];
        float4 b0 = *(const float4*)(bias + fl * 8);
        float4 b1 = *(const float4*)(bias + fl * 8 + 4);
        u16x8 o;
        o[0] = f2bu(fmaxf(acc[0] * dv + b0.x, 0.f));
        o[1] = f2bu(fmaxf(acc[1] * dv + b0.y, 0.f));
        o[2] = f2bu(fmaxf(acc[2] * dv + b0.z, 0.f));
        o[3] = f2bu(fmaxf(acc[3] * dv + b0.w, 0.f));
        o[4] = f2bu(fmaxf(acc[4] * dv + b1.x, 0.f));
        o[5] = f2bu(fmaxf(acc[5] * dv + b1.y, 0.f));
        o[6] = f2bu(fmaxf(acc[6] * dv + b1.z, 0.f));
        o[7] = f2bu(fmaxf(acc[7] * dv + b1.w, 0.f));
        *(u16x8*)(out + (size_t)node * 128 + fl * 8) = o;
    }
}

// ---- pooling + readout ----
__device__ __forceinline__ int lb(const int* a, int n, int v) {
    int lo = 0, hi = n;
    while (lo < hi) {
        int m = (lo + hi) >> 1;
        if (a[m] < v) lo = m + 1;
        else hi = m;
    }
    return lo;
}

__global__ __launch_bounds__(256) void pool_k(const unsigned short* __restrict__ h2,
                                              const int* __restrict__ batch,
                                              const float* __restrict__ Wl,
                                              const float* __restrict__ bl,
                                              float* __restrict__ out) {
    __shared__ float buf[256];
    __shared__ float part[2];
    int g = blockIdx.x, t = threadIdx.x;
    int f = t & 127, stripe = t >> 7;
    int lo = lb(batch, N_NODES, g), hi = lb(batch, N_NODES, g + 1);
    float s = 0.f;
    for (int r = lo + stripe; r < hi; r += 2)
        s += bu2f(h2[(size_t)r * 128 + f]);
    buf[t] = s;
    __syncthreads();
    if (t < 128) {
        float cf = (float)(hi - lo);
        float pooled = (buf[t] + buf[t + 128]) / fmaxf(cf, 1.f);
        float p = pooled * Wl[t];
#pragma unroll
        for (int o = 32; o > 0; o >>= 1) p += __shfl_down(p, o, 64);
        if ((t & 63) == 0) part[t >> 6] = p;
    }
    __syncthreads();
    if (t == 0) out[g] = 1.f / (1.f + expf(-(part[0] + part[1] + bl[0])));
}

extern "C" void kernel_launch(void* const* d_in, const int* in_sizes, int n_in,
                              void* d_out, int out_size, void* d_ws, size_t ws_size,
                              hipStream_t stream) {
    const float* x = (const float*)d_in[0];
    const int* ei = (const int*)d_in[1];
    const int* batch = (const int*)d_in[2];
    const float* W1 = (const float*)d_in[3];
    const float* b1 = (const float*)d_in[4];
    const float* W2 = (const float*)d_in[5];
    const float* b2 = (const float*)d_in[6];
    const float* Wl = (const float*)d_in[7];
    const float* bl = (const float*)d_in[8];
    float* out = (float*)d_out;

    char* ws = (char*)d_ws;
    int* cnt = (int*)(ws + 0x0);                             // 200 KB
    int* rowcur = (int*)(ws + 0x40000);                      // 200 KB
    float* dinv = (float*)(ws + 0x80000);                    // 200 KB
    int* bsum = (int*)(ws + 0xC0000);                        // 784 B
    int* boff = (int*)(ws + 0xC1000);                        // 784 B
    int* rowptr = (int*)(ws + 0xC2000);                      // 200 KB (+1)
    unsigned short* csr = (unsigned short*)(ws + 0x100000);  // 2.0 MB
    unsigned short* W1t = (unsigned short*)(ws + 0x300000);  // 32 KB
    unsigned short* W2t = (unsigned short*)(ws + 0x308000);  // 32 KB
    unsigned short* hs = (unsigned short*)(ws + 0x310000);   // (N+1)x128 bf16
    unsigned short* h1b = (unsigned short*)(ws + 0xF50000);  // 12.8 MB
    unsigned short* h2b = (unsigned short*)(ws + 0x1580000); // 12.8 MB

    hipMemsetAsync(cnt, 0, N_NODES * sizeof(int), stream);
    count_k<<<CNT_BLOCKS + 128, 256, 0, stream>>>(ei, cnt, W1, W2, W1t, W2t, hs);
    scan_a_k<<<NSCAN, 256, 0, stream>>>(cnt, bsum);
    scan_b_k<<<1, 256, 0, stream>>>(bsum, boff);
    scan_c_k<<<NSCAN, 256, 0, stream>>>(cnt, boff, rowptr, rowcur, csr, dinv);
    scatter_k<<<CNT_BLOCKS, 256, 0, stream>>>(ei, rowcur, csr);

    gemm_k<true><<<(N_NODES + 127) / 128, 256, 0, stream>>>(x, W1t, dinv, hs);
    agg_k<<<N_NODES / 4, 256, 0, stream>>>(hs, csr, rowptr, dinv, b1, h1b);

    gemm_k<false><<<(N_NODES + 127) / 128, 256, 0, stream>>>(h1b, W2t, dinv, hs);
    agg_k<<<N_NODES / 4, 256, 0, stream>>>(hs, csr, rowptr, dinv, b2, h2b);

    pool_k<<<NUM_GRAPHS, 256, 0, stream>>>(h2b, batch, Wl, bl, out);
}

// Round 6
// 221.274 us; speedup vs baseline: 1.2638x; 1.2638x over previous
//
#include <hip/hip_runtime.h>
#include <hip/hip_bf16.h>

#define N_NODES 50000
#define N_EDGES 800000
#define NUM_GRAPHS 512
#define MAXDEG 64
#define EPB 4096            // edges per phase-1 block
#define P1_BLOCKS 196       // ceil(N_EDGES / EPB)
#define NBUCK 256
#define NPB 196             // nodes per bucket; NPB*NBUCK = 50176 >= N_NODES

typedef short short8 __attribute__((ext_vector_type(8)));
typedef unsigned short u16x8 __attribute__((ext_vector_type(8)));
typedef float f32x4 __attribute__((ext_vector_type(4)));

__device__ __forceinline__ unsigned short f2bu(float f) {
    __hip_bfloat16 h = __float2bfloat16(f);
    return *reinterpret_cast<unsigned short*>(&h);
}
__device__ __forceinline__ float bu2f(unsigned short u) {
    unsigned int v = ((unsigned int)u) << 16;
    float f;
    __builtin_memcpy(&f, &v, 4);
    return f;
}

// ---- phase 1: bucket 4096 edges/block by dst/196 in LDS, write staged
//      bucket-ordered packed edges (coalesced) + per-(bucket,block) tables.
//      NO global atomics. Also zeros the hs sentinel row. ----
__global__ __launch_bounds__(256) void bin_k(const int* __restrict__ ei,
                                             unsigned int* __restrict__ staging,
                                             int* __restrict__ cnts_tbl,
                                             int* __restrict__ offs_tbl,
                                             unsigned short* __restrict__ hs) {
    __shared__ unsigned int st[EPB];          // 16 KB
    __shared__ int cnt[NBUCK], cur[NBUCK], scan[NBUCK];
    int b = blockIdx.x, t = threadIdx.x;
    if (b == 0 && t < 64)
        ((unsigned int*)(hs + (size_t)N_NODES * 128))[t] = 0u;
    cnt[t] = 0;
    __syncthreads();

    int e0 = b * EPB;
    int srcv[16], dstv[16], bk[16];
#pragma unroll
    for (int k = 0; k < 16; ++k) {
        int e = e0 + k * 256 + t;
        bool ok = e < N_EDGES;
        srcv[k] = ok ? ei[e] : 0;
        dstv[k] = ok ? ei[N_EDGES + e] : 0;
        bk[k] = ok ? (dstv[k] / NPB) : -1;
        if (ok) atomicAdd(&cnt[bk[k]], 1);
    }
    __syncthreads();
    scan[t] = cnt[t];
    __syncthreads();
    for (int off = 1; off < 256; off <<= 1) {
        int u = t >= off ? scan[t - off] : 0;
        __syncthreads();
        scan[t] += u;
        __syncthreads();
    }
    int excl = scan[t] - cnt[t];
    cur[t] = excl;
    cnts_tbl[t * P1_BLOCKS + b] = cnt[t];   // [bucket][block]
    offs_tbl[t * P1_BLOCKS + b] = excl;
    __syncthreads();
#pragma unroll
    for (int k = 0; k < 16; ++k) {
        if (bk[k] >= 0) {
            int pos = atomicAdd(&cur[bk[k]], 1);
            int dl = dstv[k] - bk[k] * NPB;  // < 196, fits 8 bits
            st[pos] = (unsigned int)srcv[k] | ((unsigned int)dl << 16);
        }
    }
    __syncthreads();
    unsigned int* gout = staging + (size_t)b * EPB;
    for (int i = t; i < EPB; i += 256) gout[i] = st[i];
}

// ---- phase 2: bucket b builds padded adjacency for its 196 nodes in LDS
//      (ds atomics), then writes it out coalesced. Fused: W->bf16^T. ----
__global__ __launch_bounds__(256) void adjbuild_k(const unsigned int* __restrict__ staging,
                                                  const int* __restrict__ cnts_tbl,
                                                  const int* __restrict__ offs_tbl,
                                                  unsigned short* __restrict__ adj,
                                                  int* __restrict__ cnt,
                                                  float* __restrict__ dinv,
                                                  const float* __restrict__ W1,
                                                  const float* __restrict__ W2,
                                                  unsigned short* __restrict__ W1t,
                                                  unsigned short* __restrict__ W2t) {
    int b = blockIdx.x, t = threadIdx.x;
    if (b >= NBUCK) {  // fused weight transpose-convert
        int wb = b - NBUCK;
        const float* W = wb < 64 ? W1 : W2;
        unsigned short* Wt = wb < 64 ? W1t : W2t;
        int idx = (wb & 63) * 256 + t;
        int k = idx >> 7, n = idx & 127;
        Wt[n * 128 + k] = f2bu(W[idx]);
        return;
    }
    __shared__ unsigned short adjL[NPB * MAXDEG];  // 25088 B
    __shared__ int cntL[NPB];
    __shared__ int segStart[P1_BLOCKS + 1];
    __shared__ int segOff[P1_BLOCKS];
    __shared__ int tmp[256];

    if (t < NPB) cntL[t] = 0;
    int c = t < P1_BLOCKS ? cnts_tbl[b * P1_BLOCKS + t] : 0;
    if (t < P1_BLOCKS) segOff[t] = offs_tbl[b * P1_BLOCKS + t];
    tmp[t] = c;
    __syncthreads();
    for (int off = 1; off < 256; off <<= 1) {
        int u = t >= off ? tmp[t - off] : 0;
        __syncthreads();
        tmp[t] += u;
        __syncthreads();
    }
    if (t < P1_BLOCKS) segStart[t] = tmp[t] - c;  // exclusive
    if (t == 0) segStart[P1_BLOCKS] = tmp[P1_BLOCKS - 1];
    __syncthreads();

    int T = segStart[P1_BLOCKS];
    for (int f = t; f < T; f += 256) {
        int lo = 0, hi = P1_BLOCKS;  // invariant: segStart[lo] <= f < segStart[hi]
        while (hi - lo > 1) {
            int m = (lo + hi) >> 1;
            if (segStart[m] <= f) lo = m; else hi = m;
        }
        unsigned int p = staging[(size_t)lo * EPB + segOff[lo] + (f - segStart[lo])];
        int src = p & 0xFFFF;
        int dl = p >> 16;
        int slot = atomicAdd(&cntL[dl], 1);
        if (slot < MAXDEG - 1) adjL[dl * MAXDEG + slot] = (unsigned short)src;
    }
    __syncthreads();

    int nodeBase = b * NPB;
    if (t < NPB) {
        int node = nodeBase + t;
        int cc = cntL[t];
        int ec = cc < MAXDEG - 1 ? cc : MAXDEG - 1;
        adjL[t * MAXDEG + ec] = (unsigned short)node;  // self loop
        int tot = ec + 1, tot4 = (tot + 3) & ~3;
        for (int s = tot; s < tot4; ++s) adjL[t * MAXDEG + s] = (unsigned short)N_NODES;
        if (node < N_NODES) {
            cnt[node] = cc;
            dinv[node] = rsqrtf((float)cc + 1.0f);
        }
    }
    __syncthreads();
    unsigned int* g = (unsigned int*)(adj + (size_t)nodeBase * MAXDEG);
    const unsigned int* l = (const unsigned int*)adjL;
    for (int i = t; i < NPB * MAXDEG / 2; i += 256) g[i] = l[i];
}

// ---- GEMM: C[r][c] = bf16( dinv[r] * sum_k A[r][k]*W[k][c] ), 128 rows/block ----
template <bool F32A>
__global__ __launch_bounds__(256) void gemm_k(const void* __restrict__ Ap,
                                              const unsigned short* __restrict__ Wt,
                                              const float* __restrict__ dinv,
                                              unsigned short* __restrict__ C) {
    __shared__ unsigned short Wl[128 * 136];
    int t = threadIdx.x;
    for (int idx = t; idx < 2048; idx += 256) {
        int n = idx >> 4, c = idx & 15;
        *(u16x8*)(Wl + n * 136 + c * 8) = *(const u16x8*)(Wt + n * 128 + c * 8);
    }
    __syncthreads();

    int wave = t >> 6, lane = t & 63, quad = lane >> 4, ln = lane & 15;
    int rb = blockIdx.x * 128 + wave * 16;

    short8 a[2][4];
#pragma unroll
    for (int mt = 0; mt < 2; ++mt) {
        int r = rb + mt * 64 + ln;
        r = r < N_NODES ? r : N_NODES - 1;
        if (F32A) {
            const float* arow = (const float*)Ap + (size_t)r * 128 + quad * 8;
#pragma unroll
            for (int ks = 0; ks < 4; ++ks) {
                float4 v0 = *(const float4*)(arow + ks * 32);
                float4 v1 = *(const float4*)(arow + ks * 32 + 4);
                short8 av;
                av[0] = (short)f2bu(v0.x); av[1] = (short)f2bu(v0.y);
                av[2] = (short)f2bu(v0.z); av[3] = (short)f2bu(v0.w);
                av[4] = (short)f2bu(v1.x); av[5] = (short)f2bu(v1.y);
                av[6] = (short)f2bu(v1.z); av[7] = (short)f2bu(v1.w);
                a[mt][ks] = av;
            }
        } else {
            const unsigned short* arow = (const unsigned short*)Ap + (size_t)r * 128 + quad * 8;
#pragma unroll
            for (int ks = 0; ks < 4; ++ks) a[mt][ks] = *(const short8*)(arow + ks * 32);
        }
    }

    f32x4 acc[2][8];
#pragma unroll
    for (int mt = 0; mt < 2; ++mt)
#pragma unroll
        for (int ct = 0; ct < 8; ++ct) acc[mt][ct] = (f32x4){0.f, 0.f, 0.f, 0.f};

#pragma unroll
    for (int ks = 0; ks < 4; ++ks)
#pragma unroll
        for (int ct = 0; ct < 8; ++ct) {
            short8 b = *(const short8*)(Wl + (ct * 16 + ln) * 136 + ks * 32 + quad * 8);
            acc[0][ct] = __builtin_amdgcn_mfma_f32_16x16x32_bf16(a[0][ks], b, acc[0][ct], 0, 0, 0);
            acc[1][ct] = __builtin_amdgcn_mfma_f32_16x16x32_bf16(a[1][ks], b, acc[1][ct], 0, 0, 0);
        }

#pragma unroll
    for (int mt = 0; mt < 2; ++mt) {
#pragma unroll
        for (int rr = 0; rr < 4; ++rr) {
            int r = rb + mt * 64 + quad * 4 + rr;
            if (r >= N_NODES) continue;
            float dv = dinv[r];
#pragma unroll
            for (int ct = 0; ct < 8; ++ct)
                C[(size_t)r * 128 + ct * 16 + ln] = f2bu(acc[mt][ct][rr] * dv);
        }
    }
}

// ---- aggregation: one wave/node; each quad gathers one 256B bf16 row (16B/lane) ----
__global__ __launch_bounds__(256) void agg_k(const unsigned short* __restrict__ hs,
                                             const unsigned short* __restrict__ adj,
                                             const int* __restrict__ cnt,
                                             const float* __restrict__ dinv,
                                             const float* __restrict__ bias,
                                             unsigned short* __restrict__ out) {
    int wave = threadIdx.x >> 6, lane = threadIdx.x & 63;
    int node = blockIdx.x * 4 + wave;  // grid*4 == N_NODES exactly
    int quad = lane >> 4, fl = lane & 15;
    int idx = (int)adj[node * MAXDEG + lane];
    int c = cnt[node];
    int ec = c < MAXDEG - 1 ? c : MAXDEG - 1;
    int iters = (ec + 1 + 3) >> 2;

    float acc[8];
#pragma unroll
    for (int j = 0; j < 8; ++j) acc[j] = 0.f;

    for (int i = 0; i < iters; ++i) {
        int s = __shfl(idx, i * 4 + quad, 64);
        u16x8 v = *(const u16x8*)(hs + (size_t)s * 128 + fl * 8);
#pragma unroll
        for (int j = 0; j < 8; ++j) acc[j] += bu2f(v[j]);
    }

#pragma unroll
    for (int j = 0; j < 8; ++j) {
        acc[j] += __shfl_xor(acc[j], 16, 64);
        acc[j] += __shfl_xor(acc[j], 32, 64);
    }

    if (quad == 0) {
        float dv = dinv[node];
        float4 b0 = *(const float4*)(bias + fl * 8);
        float4 b1 = *(const float4*)(bias + fl * 8 + 4);
        u16x8 o;
        o[0] = f2bu(fmaxf(acc[0] * dv + b0.x, 0.f));
        o[1] = f2bu(fmaxf(acc[1] * dv + b0.y, 0.f));
        o[2] = f2bu(fmaxf(acc[2] * dv + b0.z, 0.f));
        o[3] = f2bu(fmaxf(acc[3] * dv + b0.w, 0.f));
        o[4] = f2bu(fmaxf(acc[4] * dv + b1.x, 0.f));
        o[5] = f2bu(fmaxf(acc[5] * dv + b1.y, 0.f));
        o[6] = f2bu(fmaxf(acc[6] * dv + b1.z, 0.f));
        o[7] = f2bu(fmaxf(acc[7] * dv + b1.w, 0.f));
        *(u16x8*)(out + (size_t)node * 128 + fl * 8) = o;
    }
}

// ---- pooling + readout ----
__device__ __forceinline__ int lb(const int* a, int n, int v) {
    int lo = 0, hi = n;
    while (lo < hi) {
        int m = (lo + hi) >> 1;
        if (a[m] < v) lo = m + 1;
        else hi = m;
    }
    return lo;
}

__global__ __launch_bounds__(256) void pool_k(const unsigned short* __restrict__ h2,
                                              const int* __restrict__ batch,
                                              const float* __restrict__ Wl,
                                              const float* __restrict__ bl,
                                              float* __restrict__ out) {
    __shared__ float buf[256];
    __shared__ float part[2];
    int g = blockIdx.x, t = threadIdx.x;
    int f = t & 127, stripe = t >> 7;
    int lo = lb(batch, N_NODES, g), hi = lb(batch, N_NODES, g + 1);
    float s = 0.f;
    for (int r = lo + stripe; r < hi; r += 2)
        s += bu2f(h2[(size_t)r * 128 + f]);
    buf[t] = s;
    __syncthreads();
    if (t < 128) {
        float cf = (float)(hi - lo);
        float pooled = (buf[t] + buf[t + 128]) / fmaxf(cf, 1.f);
        float p = pooled * Wl[t];
#pragma unroll
        for (int o = 32; o > 0; o >>= 1) p += __shfl_down(p, o, 64);
        if ((t & 63) == 0) part[t >> 6] = p;
    }
    __syncthreads();
    if (t == 0) out[g] = 1.f / (1.f + expf(-(part[0] + part[1] + bl[0])));
}

extern "C" void kernel_launch(void* const* d_in, const int* in_sizes, int n_in,
                              void* d_out, int out_size, void* d_ws, size_t ws_size,
                              hipStream_t stream) {
    const float* x = (const float*)d_in[0];
    const int* ei = (const int*)d_in[1];
    const int* batch = (const int*)d_in[2];
    const float* W1 = (const float*)d_in[3];
    const float* b1 = (const float*)d_in[4];
    const float* W2 = (const float*)d_in[5];
    const float* b2 = (const float*)d_in[6];
    const float* Wl = (const float*)d_in[7];
    const float* bl = (const float*)d_in[8];
    float* out = (float*)d_out;

    char* ws = (char*)d_ws;
    unsigned int* staging = (unsigned int*)(ws + 0x0);       // 196*4096*4 = 3.21 MB
    int* cnts_tbl = (int*)(ws + 0x310000);                   // 256*196*4 = 200704 B
    int* offs_tbl = (int*)(ws + 0x341000);                   // 200704 B
    unsigned short* adj = (unsigned short*)(ws + 0x372000);  // 50176*64*2 = 6.42 MB
    int* cnt = (int*)(ws + 0x992000);                        // 200 KB
    float* dinv = (float*)(ws + 0x9C3000);                   // 200 KB
    unsigned short* W1t = (unsigned short*)(ws + 0x9F4000);  // 32 KB
    unsigned short* W2t = (unsigned short*)(ws + 0x9FC000);  // 32 KB
    unsigned short* hs = (unsigned short*)(ws + 0xA04000);   // (N+1)x128 bf16
    unsigned short* h1b = (unsigned short*)(ws + 0x1640000); // 12.8 MB
    unsigned short* h2b = (unsigned short*)(ws + 0x2280000); // 12.8 MB

    bin_k<<<P1_BLOCKS, 256, 0, stream>>>(ei, staging, cnts_tbl, offs_tbl, hs);
    adjbuild_k<<<NBUCK + 128, 256, 0, stream>>>(staging, cnts_tbl, offs_tbl,
                                                adj, cnt, dinv, W1, W2, W1t, W2t);

    gemm_k<true><<<(N_NODES + 127) / 128, 256, 0, stream>>>(x, W1t, dinv, hs);
    agg_k<<<N_NODES / 4, 256, 0, stream>>>(hs, adj, cnt, dinv, b1, h1b);

    gemm_k<false><<<(N_NODES + 127) / 128, 256, 0, stream>>>(h1b, W2t, dinv, hs);
    agg_k<<<N_NODES / 4, 256, 0, stream>>>(hs, adj, cnt, dinv, b2, h2b);

    pool_k<<<NUM_GRAPHS, 256, 0, stream>>>(h2b, batch, Wl, bl, out);
}

// Round 7
// 206.059 us; speedup vs baseline: 1.3571x; 1.0738x over previous
//
#include <hip/hip_runtime.h>
#include <hip/hip_bf16.h>

#define N_NODES 50000
#define N_EDGES 800000
#define NUM_GRAPHS 512
#define MAXDEG 64
#define EPB 4096            // edges per phase-1 block
#define P1_BLOCKS 196       // ceil(N_EDGES / EPB)
#define NBUCK 256
#define NPB 196             // nodes per bucket; NPB*NBUCK = 50176 >= N_NODES

typedef short short8 __attribute__((ext_vector_type(8)));
typedef unsigned short u16x8 __attribute__((ext_vector_type(8)));
typedef float f32x4 __attribute__((ext_vector_type(4)));

__device__ __forceinline__ unsigned short f2bu(float f) {
    __hip_bfloat16 h = __float2bfloat16(f);
    return *reinterpret_cast<unsigned short*>(&h);
}
__device__ __forceinline__ float bu2f(unsigned short u) {
    unsigned int v = ((unsigned int)u) << 16;
    float f;
    __builtin_memcpy(&f, &v, 4);
    return f;
}

// ---- phase 1: bucket 4096 edges/block by dst/196 in LDS, write staged
//      bucket-ordered packed edges (coalesced) + per-(bucket,block) tables.
//      NO global atomics. Also zeros the hs1/hs2 sentinel rows. ----
__global__ __launch_bounds__(256) void bin_k(const int* __restrict__ ei,
                                             unsigned int* __restrict__ staging,
                                             int* __restrict__ cnts_tbl,
                                             int* __restrict__ offs_tbl,
                                             unsigned short* __restrict__ hs1,
                                             unsigned short* __restrict__ hs2) {
    __shared__ unsigned int st[EPB];          // 16 KB
    __shared__ int cnt[NBUCK], cur[NBUCK], scan[NBUCK];
    int b = blockIdx.x, t = threadIdx.x;
    if (b == 0 && t < 64)
        ((unsigned int*)(hs1 + (size_t)N_NODES * 128))[t] = 0u;
    if (b == 1 && t < 64)
        ((unsigned int*)(hs2 + (size_t)N_NODES * 128))[t] = 0u;
    cnt[t] = 0;
    __syncthreads();

    int e0 = b * EPB;
    int srcv[16], dstv[16], bk[16];
#pragma unroll
    for (int k = 0; k < 16; ++k) {
        int e = e0 + k * 256 + t;
        bool ok = e < N_EDGES;
        srcv[k] = ok ? ei[e] : 0;
        dstv[k] = ok ? ei[N_EDGES + e] : 0;
        bk[k] = ok ? (dstv[k] / NPB) : -1;
        if (ok) atomicAdd(&cnt[bk[k]], 1);
    }
    __syncthreads();
    scan[t] = cnt[t];
    __syncthreads();
    for (int off = 1; off < 256; off <<= 1) {
        int u = t >= off ? scan[t - off] : 0;
        __syncthreads();
        scan[t] += u;
        __syncthreads();
    }
    int excl = scan[t] - cnt[t];
    cur[t] = excl;
    cnts_tbl[t * P1_BLOCKS + b] = cnt[t];   // [bucket][block]
    offs_tbl[t * P1_BLOCKS + b] = excl;
    __syncthreads();
#pragma unroll
    for (int k = 0; k < 16; ++k) {
        if (bk[k] >= 0) {
            int pos = atomicAdd(&cur[bk[k]], 1);
            int dl = dstv[k] - bk[k] * NPB;  // < 196, fits 8 bits
            st[pos] = (unsigned int)srcv[k] | ((unsigned int)dl << 16);
        }
    }
    __syncthreads();
    unsigned int* gout = staging + (size_t)b * EPB;
    for (int i = t; i < EPB; i += 256) gout[i] = st[i];
}

// ---- phase 2: bucket b builds padded adjacency for its 196 nodes in LDS
//      (ds atomics), then writes it out coalesced. Fused: W->bf16^T. ----
__global__ __launch_bounds__(256) void adjbuild_k(const unsigned int* __restrict__ staging,
                                                  const int* __restrict__ cnts_tbl,
                                                  const int* __restrict__ offs_tbl,
                                                  unsigned short* __restrict__ adj,
                                                  int* __restrict__ cnt,
                                                  float* __restrict__ dinv,
                                                  const float* __restrict__ W1,
                                                  const float* __restrict__ W2,
                                                  unsigned short* __restrict__ W1t,
                                                  unsigned short* __restrict__ W2t) {
    int b = blockIdx.x, t = threadIdx.x;
    if (b >= NBUCK) {  // fused weight transpose-convert
        int wb = b - NBUCK;
        const float* W = wb < 64 ? W1 : W2;
        unsigned short* Wt = wb < 64 ? W1t : W2t;
        int idx = (wb & 63) * 256 + t;
        int k = idx >> 7, n = idx & 127;
        Wt[n * 128 + k] = f2bu(W[idx]);
        return;
    }
    __shared__ unsigned short adjL[NPB * MAXDEG];  // 25088 B
    __shared__ int cntL[NPB];
    __shared__ int segStart[P1_BLOCKS + 1];
    __shared__ int segOff[P1_BLOCKS];
    __shared__ int tmp[256];

    if (t < NPB) cntL[t] = 0;
    int c = t < P1_BLOCKS ? cnts_tbl[b * P1_BLOCKS + t] : 0;
    if (t < P1_BLOCKS) segOff[t] = offs_tbl[b * P1_BLOCKS + t];
    tmp[t] = c;
    __syncthreads();
    for (int off = 1; off < 256; off <<= 1) {
        int u = t >= off ? tmp[t - off] : 0;
        __syncthreads();
        tmp[t] += u;
        __syncthreads();
    }
    if (t < P1_BLOCKS) segStart[t] = tmp[t] - c;  // exclusive
    if (t == 0) segStart[P1_BLOCKS] = tmp[P1_BLOCKS - 1];
    __syncthreads();

    int T = segStart[P1_BLOCKS];
    for (int f = t; f < T; f += 256) {
        int lo = 0, hi = P1_BLOCKS;  // invariant: segStart[lo] <= f < segStart[hi]
        while (hi - lo > 1) {
            int m = (lo + hi) >> 1;
            if (segStart[m] <= f) lo = m; else hi = m;
        }
        unsigned int p = staging[(size_t)lo * EPB + segOff[lo] + (f - segStart[lo])];
        int src = p & 0xFFFF;
        int dl = p >> 16;
        int slot = atomicAdd(&cntL[dl], 1);
        if (slot < MAXDEG - 1) adjL[dl * MAXDEG + slot] = (unsigned short)src;
    }
    __syncthreads();

    int nodeBase = b * NPB;
    if (t < NPB) {
        int node = nodeBase + t;
        int cc = cntL[t];
        int ec = cc < MAXDEG - 1 ? cc : MAXDEG - 1;
        adjL[t * MAXDEG + ec] = (unsigned short)node;  // self loop
        int tot = ec + 1, tot4 = (tot + 3) & ~3;
        for (int s = tot; s < tot4; ++s) adjL[t * MAXDEG + s] = (unsigned short)N_NODES;
        if (node < N_NODES) {
            cnt[node] = cc;
            dinv[node] = rsqrtf((float)cc + 1.0f);
        }
    }
    __syncthreads();
    unsigned int* g = (unsigned int*)(adj + (size_t)nodeBase * MAXDEG);
    const unsigned int* l = (const unsigned int*)adjL;
    for (int i = t; i < NPB * MAXDEG / 2; i += 256) g[i] = l[i];
}

// ---- GEMM1: hs1[r][c] = bf16( dinv[r] * sum_k x[r][k]*W1[k][c] ), fp32 A ----
__global__ __launch_bounds__(256) void gemm_k(const float* __restrict__ Ap,
                                              const unsigned short* __restrict__ Wt,
                                              const float* __restrict__ dinv,
                                              unsigned short* __restrict__ C) {
    __shared__ unsigned short Wl[128 * 136];
    int t = threadIdx.x;
    for (int idx = t; idx < 2048; idx += 256) {
        int n = idx >> 4, c = idx & 15;
        *(u16x8*)(Wl + n * 136 + c * 8) = *(const u16x8*)(Wt + n * 128 + c * 8);
    }
    __syncthreads();

    int wave = t >> 6, lane = t & 63, quad = lane >> 4, ln = lane & 15;
    int rb = blockIdx.x * 128 + wave * 16;

    short8 a[2][4];
#pragma unroll
    for (int mt = 0; mt < 2; ++mt) {
        int r = rb + mt * 64 + ln;
        r = r < N_NODES ? r : N_NODES - 1;
        const float* arow = Ap + (size_t)r * 128 + quad * 8;
#pragma unroll
        for (int ks = 0; ks < 4; ++ks) {
            float4 v0 = *(const float4*)(arow + ks * 32);
            float4 v1 = *(const float4*)(arow + ks * 32 + 4);
            short8 av;
            av[0] = (short)f2bu(v0.x); av[1] = (short)f2bu(v0.y);
            av[2] = (short)f2bu(v0.z); av[3] = (short)f2bu(v0.w);
            av[4] = (short)f2bu(v1.x); av[5] = (short)f2bu(v1.y);
            av[6] = (short)f2bu(v1.z); av[7] = (short)f2bu(v1.w);
            a[mt][ks] = av;
        }
    }

    f32x4 acc[2][8];
#pragma unroll
    for (int mt = 0; mt < 2; ++mt)
#pragma unroll
        for (int ct = 0; ct < 8; ++ct) acc[mt][ct] = (f32x4){0.f, 0.f, 0.f, 0.f};

#pragma unroll
    for (int ks = 0; ks < 4; ++ks)
#pragma unroll
        for (int ct = 0; ct < 8; ++ct) {
            short8 b = *(const short8*)(Wl + (ct * 16 + ln) * 136 + ks * 32 + quad * 8);
            acc[0][ct] = __builtin_amdgcn_mfma_f32_16x16x32_bf16(a[0][ks], b, acc[0][ct], 0, 0, 0);
            acc[1][ct] = __builtin_amdgcn_mfma_f32_16x16x32_bf16(a[1][ks], b, acc[1][ct], 0, 0, 0);
        }

#pragma unroll
    for (int mt = 0; mt < 2; ++mt) {
#pragma unroll
        for (int rr = 0; rr < 4; ++rr) {
            int r = rb + mt * 64 + quad * 4 + rr;
            if (r >= N_NODES) continue;
            float dv = dinv[r];
#pragma unroll
            for (int ct = 0; ct < 8; ++ct)
                C[(size_t)r * 128 + ct * 16 + ln] = f2bu(acc[mt][ct][rr] * dv);
        }
    }
}

// ---- fused layer: per block of 16 nodes, aggregate h1 = relu(dinv*sum + b1)
//      into an LDS tile, then MFMA tile x W2 and write hs2 = bf16(h1*W2*dinv).
//      Gather loop unrolled x2 (8 rows in flight per wave). ----
__global__ __launch_bounds__(256) void agg_gemm_k(const unsigned short* __restrict__ hs1,
                                                  const unsigned short* __restrict__ adj,
                                                  const int* __restrict__ cnt,
                                                  const float* __restrict__ dinv,
                                                  const float* __restrict__ bias,
                                                  const unsigned short* __restrict__ W2t,
                                                  unsigned short* __restrict__ hs2) {
    __shared__ unsigned short Wl[128 * 136];   // 34.8 KB
    __shared__ unsigned short h1t[16 * 136];   // 4.3 KB
    int t = threadIdx.x, wave = t >> 6, lane = t & 63;
    int quad = lane >> 4, fl = lane & 15;
    for (int idx = t; idx < 2048; idx += 256) {
        int n = idx >> 4, c = idx & 15;
        *(u16x8*)(Wl + n * 136 + c * 8) = *(const u16x8*)(W2t + n * 128 + c * 8);
    }
    int nb = blockIdx.x * 16;  // 3125 * 16 == N_NODES

    float4 b0 = *(const float4*)(bias + fl * 8);
    float4 b1f = *(const float4*)(bias + fl * 8 + 4);

#pragma unroll
    for (int q = 0; q < 4; ++q) {
        int lr = wave * 4 + q;
        int node = nb + lr;
        int idxv = (int)adj[node * MAXDEG + lane];
        int c = cnt[node];
        int ec = c < MAXDEG - 1 ? c : MAXDEG - 1;
        int iters = (ec + 4) >> 2;

        float acc[8];
#pragma unroll
        for (int j = 0; j < 8; ++j) acc[j] = 0.f;

        int i = 0;
        for (; i + 2 <= iters; i += 2) {
            int s0 = __shfl(idxv, i * 4 + quad, 64);
            int s1 = __shfl(idxv, i * 4 + 4 + quad, 64);
            u16x8 v0 = *(const u16x8*)(hs1 + (size_t)s0 * 128 + fl * 8);
            u16x8 v1 = *(const u16x8*)(hs1 + (size_t)s1 * 128 + fl * 8);
#pragma unroll
            for (int j = 0; j < 8; ++j) acc[j] += bu2f(v0[j]) + bu2f(v1[j]);
        }
        if (i < iters) {
            int s0 = __shfl(idxv, i * 4 + quad, 64);
            u16x8 v0 = *(const u16x8*)(hs1 + (size_t)s0 * 128 + fl * 8);
#pragma unroll
            for (int j = 0; j < 8; ++j) acc[j] += bu2f(v0[j]);
        }
#pragma unroll
        for (int j = 0; j < 8; ++j) {
            acc[j] += __shfl_xor(acc[j], 16, 64);
            acc[j] += __shfl_xor(acc[j], 32, 64);
        }
        if (quad == 0) {
            float dv = dinv[node];
            u16x8 o;
            o[0] = f2bu(fmaxf(acc[0] * dv + b0.x, 0.f));
            o[1] = f2bu(fmaxf(acc[1] * dv + b0.y, 0.f));
            o[2] = f2bu(fmaxf(acc[2] * dv + b0.z, 0.f));
            o[3] = f2bu(fmaxf(acc[3] * dv + b0.w, 0.f));
            o[4] = f2bu(fmaxf(acc[4] * dv + b1f.x, 0.f));
            o[5] = f2bu(fmaxf(acc[5] * dv + b1f.y, 0.f));
            o[6] = f2bu(fmaxf(acc[6] * dv + b1f.z, 0.f));
            o[7] = f2bu(fmaxf(acc[7] * dv + b1f.w, 0.f));
            *(u16x8*)(h1t + lr * 136 + fl * 8) = o;
        }
    }
    __syncthreads();

    // MFMA: wave handles cols [wave*32, wave*32+32)
    int ln = fl;
    short8 a[4];
#pragma unroll
    for (int ks = 0; ks < 4; ++ks)
        a[ks] = *(const short8*)(h1t + ln * 136 + ks * 32 + quad * 8);

    f32x4 acc2[2];
    acc2[0] = (f32x4){0.f, 0.f, 0.f, 0.f};
    acc2[1] = (f32x4){0.f, 0.f, 0.f, 0.f};
#pragma unroll
    for (int ks = 0; ks < 4; ++ks)
#pragma unroll
        for (int ct = 0; ct < 2; ++ct) {
            short8 b = *(const short8*)(Wl + (wave * 32 + ct * 16 + ln) * 136 + ks * 32 + quad * 8);
            acc2[ct] = __builtin_amdgcn_mfma_f32_16x16x32_bf16(a[ks], b, acc2[ct], 0, 0, 0);
        }

    float dvr[4];
#pragma unroll
    for (int rr = 0; rr < 4; ++rr) dvr[rr] = dinv[nb + quad * 4 + rr];
#pragma unroll
    for (int ct = 0; ct < 2; ++ct)
#pragma unroll
        for (int rr = 0; rr < 4; ++rr) {
            int node = nb + quad * 4 + rr;
            hs2[(size_t)node * 128 + wave * 32 + ct * 16 + ln] = f2bu(acc2[ct][rr] * dvr[rr]);
        }
}

// ---- aggregation (layer 2): one wave/node, gather unrolled x2 ----
__global__ __launch_bounds__(256) void agg_k(const unsigned short* __restrict__ hs,
                                             const unsigned short* __restrict__ adj,
                                             const int* __restrict__ cnt,
                                             const float* __restrict__ dinv,
                                             const float* __restrict__ bias,
                                             unsigned short* __restrict__ out) {
    int wave = threadIdx.x >> 6, lane = threadIdx.x & 63;
    int node = blockIdx.x * 4 + wave;  // grid*4 == N_NODES exactly
    int quad = lane >> 4, fl = lane & 15;
    int idx = (int)adj[node * MAXDEG + lane];
    int c = cnt[node];
    int ec = c < MAXDEG - 1 ? c : MAXDEG - 1;
    int iters = (ec + 4) >> 2;

    float acc[8];
#pragma unroll
    for (int j = 0; j < 8; ++j) acc[j] = 0.f;

    int i = 0;
    for (; i + 2 <= iters; i += 2) {
        int s0 = __shfl(idx, i * 4 + quad, 64);
        int s1 = __shfl(idx, i * 4 + 4 + quad, 64);
        u16x8 v0 = *(const u16x8*)(hs + (size_t)s0 * 128 + fl * 8);
        u16x8 v1 = *(const u16x8*)(hs + (size_t)s1 * 128 + fl * 8);
#pragma unroll
        for (int j = 0; j < 8; ++j) acc[j] += bu2f(v0[j]) + bu2f(v1[j]);
    }
    if (i < iters) {
        int s0 = __shfl(idx, i * 4 + quad, 64);
        u16x8 v0 = *(const u16x8*)(hs + (size_t)s0 * 128 + fl * 8);
#pragma unroll
        for (int j = 0; j < 8; ++j) acc[j] += bu2f(v0[j]);
    }

#pragma unroll
    for (int j = 0; j < 8; ++j) {
        acc[j] += __shfl_xor(acc[j], 16, 64);
        acc[j] += __shfl_xor(acc[j], 32, 64);
    }

    if (quad == 0) {
        float dv = dinv[node];
        float4 b0 = *(const float4*)(bias + fl * 8);
        float4 b1 = *(const float4*)(bias + fl * 8 + 4);
        u16x8 o;
        o[0] = f2bu(fmaxf(acc[0] * dv + b0.x, 0.f));
        o[1] = f2bu(fmaxf(acc[1] * dv + b0.y, 0.f));
        o[2] = f2bu(fmaxf(acc[2] * dv + b0.z, 0.f));
        o[3] = f2bu(fmaxf(acc[3] * dv + b0.w, 0.f));
        o[4] = f2bu(fmaxf(acc[4] * dv + b1.x, 0.f));
        o[5] = f2bu(fmaxf(acc[5] * dv + b1.y, 0.f));
        o[6] = f2bu(fmaxf(acc[6] * dv + b1.z, 0.f));
        o[7] = f2bu(fmaxf(acc[7] * dv + b1.w, 0.f));
        *(u16x8*)(out + (size_t)node * 128 + fl * 8) = o;
    }
}

// ---- pooling + readout: 256 thr = 64 feature-pairs x 4 row-stripes ----
__device__ __forceinline__ int lb(const int* a, int n, int v) {
    int lo = 0, hi = n;
    while (lo < hi) {
        int m = (lo + hi) >> 1;
        if (a[m] < v) lo = m + 1;
        else hi = m;
    }
    return lo;
}

__global__ __launch_bounds__(256) void pool_k(const unsigned short* __restrict__ h2,
                                              const int* __restrict__ batch,
                                              const float* __restrict__ Wl,
                                              const float* __restrict__ bl,
                                              float* __restrict__ out) {
    __shared__ float buf[256];
    __shared__ float part[4];
    int g = blockIdx.x, t = threadIdx.x;
    int fp = t & 63, stripe = t >> 6;  // feature pair fp -> features 2fp, 2fp+1
    int lo = lb(batch, N_NODES, g), hi = lb(batch, N_NODES, g + 1);
    float s0 = 0.f, s1 = 0.f;
    for (int r = lo + stripe; r < hi; r += 4) {
        unsigned int u = *(const unsigned int*)(h2 + (size_t)r * 128 + fp * 2);
        s0 += bu2f((unsigned short)(u & 0xFFFF));
        s1 += bu2f((unsigned short)(u >> 16));
    }
    float p = s0 * Wl[fp * 2] + s1 * Wl[fp * 2 + 1];
#pragma unroll
    for (int o = 32; o > 0; o >>= 1) p += __shfl_down(p, o, 64);
    if ((t & 63) == 0) part[t >> 6] = p;
    __syncthreads();
    if (t == 0) {
        float cf = (float)(hi - lo);
        float z = (part[0] + part[1] + part[2] + part[3]) / fmaxf(cf, 1.f) + bl[0];
        out[g] = 1.f / (1.f + expf(-z));
    }
    (void)buf;
}

extern "C" void kernel_launch(void* const* d_in, const int* in_sizes, int n_in,
                              void* d_out, int out_size, void* d_ws, size_t ws_size,
                              hipStream_t stream) {
    const float* x = (const float*)d_in[0];
    const int* ei = (const int*)d_in[1];
    const int* batch = (const int*)d_in[2];
    const float* W1 = (const float*)d_in[3];
    const float* b1 = (const float*)d_in[4];
    const float* W2 = (const float*)d_in[5];
    const float* b2 = (const float*)d_in[6];
    const float* Wl = (const float*)d_in[7];
    const float* bl = (const float*)d_in[8];
    float* out = (float*)d_out;

    char* ws = (char*)d_ws;
    unsigned int* staging = (unsigned int*)(ws + 0x0);       // 3.21 MB
    int* cnts_tbl = (int*)(ws + 0x310000);                   // 200704 B
    int* offs_tbl = (int*)(ws + 0x341000);                   // 200704 B
    unsigned short* adj = (unsigned short*)(ws + 0x372000);  // 6.42 MB
    int* cnt = (int*)(ws + 0x992000);                        // 200 KB
    float* dinv = (float*)(ws + 0x9C3000);                   // 200 KB
    unsigned short* W1t = (unsigned short*)(ws + 0x9F4000);  // 32 KB
    unsigned short* W2t = (unsigned short*)(ws + 0x9FC000);  // 32 KB
    unsigned short* hs1 = (unsigned short*)(ws + 0xA04000);  // (N+1)x128 bf16
    unsigned short* hs2 = (unsigned short*)(ws + 0x1640000); // (N+1)x128 bf16
    unsigned short* h2b = (unsigned short*)(ws + 0x2280000); // 12.8 MB

    bin_k<<<P1_BLOCKS, 256, 0, stream>>>(ei, staging, cnts_tbl, offs_tbl, hs1, hs2);
    adjbuild_k<<<NBUCK + 128, 256, 0, stream>>>(staging, cnts_tbl, offs_tbl,
                                                adj, cnt, dinv, W1, W2, W1t, W2t);

    gemm_k<<<(N_NODES + 127) / 128, 256, 0, stream>>>(x, W1t, dinv, hs1);
    agg_gemm_k<<<N_NODES / 16, 256, 0, stream>>>(hs1, adj, cnt, dinv, b1, W2t, hs2);
    agg_k<<<N_NODES / 4, 256, 0, stream>>>(hs2, adj, cnt, dinv, b2, h2b);

    pool_k<<<NUM_GRAPHS, 256, 0, stream>>>(h2b, batch, Wl, bl, out);
}